// Round 9
// baseline (251.631 us; speedup 1.0000x reference)
//
#include <hip/hip_runtime.h>

#define FUZZ 2187
#define NFEAT 7
#define MID 512
#define NCLS 10
#define BATCH 4096
#define SSTR 2192   // padded row stride for S (21 rows)

constexpr int pw3(int e) { int r = 1; while (e--) r *= 3; return r; }

// ---------------------------------------------------------------------------
// Kernel 1 (atomic-free, high-TLP): S[g=3j+m][n] = sum_{k:digit_j(k)=m} wei[k*7+j,n]
// digit_j(k) = (k / 3^(6-j)) % 3. Enumerate e = hi*PL + lo in [0,729),
// k = (hi*3+m)*PL + lo, PL = 3^(6-j) compile-time via template<J> -> e/PL is
// a magic-mul, no runtime div. Grid (35 n-tiles x 64, 21 groups) x 512 thr:
// 8 waves/block split the 729 k's (waves 0..6: 91 = 7x13, wave 7: 92),
// LDS-reduce, ONE writer per (g,n) -> plain store. 5880 waves = 23/CU; loads
// issued in explicit 13-deep register bursts (round-7-proven pattern) ->
// ~78 KB/CU in flight -> BW-bound. Round-6's failure was 735 single-wave
// blocks + collapsed bursts (VGPR=12, 333 GB/s); this fixes both.
// Block (0,0) also zeroes K+T/H/v/w (5408 floats) for later atomicAdds.
// ---------------------------------------------------------------------------
template<int J>
__device__ __forceinline__ float group_range(const float* __restrict__ wei,
                                             int m, int n, int e0, int cnt) {
    constexpr int PL = pw3(6 - J);
    float acc = 0.f;
    int e = e0;
    int eend = e0 + cnt;
    while (e + 13 <= eend) {
        float v[13];
#pragma unroll
        for (int u = 0; u < 13; ++u) {
            int ee = e + u;
            int hi = ee / PL;               // compile-time PL -> magic mul
            int lo = ee - hi * PL;
            int k  = (hi * 3 + m) * PL + lo;
            v[u] = wei[((size_t)k * 7 + J) * FUZZ + n];
        }
#pragma unroll
        for (int u = 0; u < 13; ++u) acc += v[u];
        e += 13;
    }
    while (e < eend) {                      // only wave 7 hits this (1 iter)
        int hi = e / PL;
        int lo = e - hi * PL;
        int k  = (hi * 3 + m) * PL + lo;
        acc += wei[((size_t)k * 7 + J) * FUZZ + n];
        ++e;
    }
    return acc;
}

__global__ __launch_bounds__(512) void k_reduce_wei(const float* __restrict__ wei,
                                                    float* __restrict__ S,
                                                    float* __restrict__ Kz) {
    int g = blockIdx.y;                     // 0..20: g = 3*j + m
    int tid = threadIdx.x;
    int w = tid >> 6, lane = tid & 63;
    if (g == 0 && blockIdx.x == 0) {        // zero K(5120)+T/H/v/w(288)
        for (int z = tid; z < NCLS * MID + 288; z += 512) Kz[z] = 0.f;
    }
    int n = blockIdx.x * 64 + lane;
    int j = g / 3, m = g % 3;               // block-uniform -> scalar
    float acc = 0.f;
    int e0 = w * 91;
    int cnt = (w == 7) ? 92 : 91;           // 729 = 7*91 + 92
    if (n < FUZZ) {
        switch (j) {
            case 0: acc = group_range<0>(wei, m, n, e0, cnt); break;
            case 1: acc = group_range<1>(wei, m, n, e0, cnt); break;
            case 2: acc = group_range<2>(wei, m, n, e0, cnt); break;
            case 3: acc = group_range<3>(wei, m, n, e0, cnt); break;
            case 4: acc = group_range<4>(wei, m, n, e0, cnt); break;
            case 5: acc = group_range<5>(wei, m, n, e0, cnt); break;
            default: acc = group_range<6>(wei, m, n, e0, cnt); break;
        }
    }
    __shared__ float red[8][64];
    red[w][lane] = acc;
    __syncthreads();
    if (w == 0 && n < FUZZ) {
        float s = 0.f;
#pragma unroll
        for (int ww = 0; ww < 8; ++ww) s += red[ww][lane];
        S[g * SSTR + n] = s;
    }
}

__device__ __forceinline__ float wave_sum(float v) {
#pragma unroll
    for (int off = 32; off > 0; off >>= 1) v += __shfl_down(v, off, 64);
    return v;
}

// ---------------------------------------------------------------------------
// Kernel 2 (mixed roles by blockIdx.x):
//   gid in [0,512):      SW1[t][i=gid] = sum_n S[t,n]*W1[i,n]; ws1[i]
//                        (4-wave block, LDS reduce) — unchanged, verified.
//   gid in [512,512+270): K partials. idx=(gid-512): c=idx/27, n-chunk of 81.
//                        Thread tid owns i=tid and i=tid+256; atomicAdd into
//                        K (zeroed by k_reduce_wei block (0,0)).
// K = W3*W2 (10x512): G*W3^T == SW1*K^T, eliminating the old k_g dispatch.
// ---------------------------------------------------------------------------
__global__ __launch_bounds__(256) void k_sw1(const float* __restrict__ S,
                                             const float* __restrict__ W1,
                                             const float* __restrict__ W2,
                                             const float* __restrict__ W3,
                                             float* __restrict__ SW1,
                                             float* __restrict__ ws1,
                                             float* __restrict__ K) {
    int gid = blockIdx.x;
    int tid = threadIdx.x;
    if (gid >= MID) {
        int idx = gid - MID;        // 0..269
        int c = idx / 27;
        int chunk = idx % 27;
        int n0 = chunk * 81;
        float acc0 = 0.f, acc1 = 0.f;
        const float* w3row = W3 + (size_t)c * FUZZ;
        const float* w2col = W2 + tid;
#pragma unroll 9
        for (int n = n0; n < n0 + 81; ++n) {
            float w3 = w3row[n];
            acc0 += w3 * w2col[(size_t)n * MID];
            acc1 += w3 * w2col[(size_t)n * MID + 256];
        }
        atomicAdd(&K[c * MID + tid],       acc0);
        atomicAdd(&K[c * MID + tid + 256], acc1);
        return;
    }
    int i = gid;
    float acc[21];
    float aw = 0.f;
#pragma unroll
    for (int t = 0; t < 21; ++t) acc[t] = 0.f;
    const float* w1row = W1 + (size_t)i * FUZZ;
    for (int n = tid; n < FUZZ; n += 256) {
        float w1 = w1row[n];
        aw += w1;
#pragma unroll
        for (int t = 0; t < 21; ++t) acc[t] += S[t * SSTR + n] * w1;
    }
#pragma unroll
    for (int t = 0; t < 21; ++t) acc[t] = wave_sum(acc[t]);
    aw = wave_sum(aw);
    __shared__ float red[4][22];
    int w = tid >> 6, lane = tid & 63;
    if (lane == 0) {
#pragma unroll
        for (int t = 0; t < 21; ++t) red[w][t] = acc[t];
        red[w][21] = aw;
    }
    __syncthreads();
    if (tid < 22) {
        float s = red[0][tid] + red[1][tid] + red[2][tid] + red[3][tid];
        if (tid < 21) SW1[tid * MID + i] = s;
        else          ws1[i] = s;
    }
}

// ---------------------------------------------------------------------------
// Kernel 3: H[jm][c] = sum_n S[jm,n]*W3[c,n] + sum_i SW1[jm,i]*K[c,i]
//           v[c] = sum_n W3[c,n] + sum_i ws1[i]*K[c,i]
//           w[c] = sum_i b1[i]*K[c,i] + sum_n b2[n]*W3[c,n] + b3[c]
//           T[jm] = sum_n S[jm,n]               (blockIdx.x == 10)
// Grid (11, 9): n split into 9 chunks of 243; chunks 0..7 additionally own
// i = chunk*64+lane (one i per lane, covers all 512). atomicAdd epilogue
// into T/H/v/w (zeroed by k_reduce_wei).
// ---------------------------------------------------------------------------
__global__ __launch_bounds__(64) void k_h(const float* __restrict__ S,
                                          const float* __restrict__ SW1,
                                          const float* __restrict__ ws1,
                                          const float* __restrict__ K,
                                          const float* __restrict__ b1,
                                          const float* __restrict__ b2,
                                          const float* __restrict__ b3,
                                          const float* __restrict__ W3,
                                          float* __restrict__ H,
                                          float* __restrict__ v,
                                          float* __restrict__ w,
                                          float* __restrict__ T) {
    int c = blockIdx.x;
    int chunk = blockIdx.y;
    int lane = threadIdx.x;
    int n0 = chunk * 243;
    if (c < NCLS) {
        float acc[21];
        float av = 0.f, aw = 0.f;
#pragma unroll
        for (int t = 0; t < 21; ++t) acc[t] = 0.f;
        const float* w3row = W3 + (size_t)c * FUZZ;
        for (int n = n0 + lane; n < n0 + 243; n += 64) {
            float w3 = w3row[n];
            av += w3;
            aw += b2[n] * w3;
#pragma unroll
            for (int t = 0; t < 21; ++t)
                acc[t] += S[t * SSTR + n] * w3;
        }
        if (chunk < 8) {
            int i = chunk * 64 + lane;      // each lane exactly one i
            float kk = K[c * MID + i];
            av += ws1[i] * kk;
            aw += b1[i] * kk;
#pragma unroll
            for (int t = 0; t < 21; ++t)
                acc[t] += SW1[t * MID + i] * kk;
        }
#pragma unroll
        for (int t = 0; t < 21; ++t) acc[t] = wave_sum(acc[t]);
        av = wave_sum(av);
        aw = wave_sum(aw);
        if (lane == 0) {
#pragma unroll
            for (int t = 0; t < 21; ++t) atomicAdd(&H[t * NCLS + c], acc[t]);
            atomicAdd(&v[c], av);
            atomicAdd(&w[c], aw + (chunk == 0 ? b3[c] : 0.f));
        }
    } else {
        float acc[21];
#pragma unroll
        for (int t = 0; t < 21; ++t) acc[t] = 0.f;
        for (int n = n0 + lane; n < n0 + 243; n += 64) {
#pragma unroll
            for (int t = 0; t < 21; ++t) acc[t] += S[t * SSTR + n];
        }
#pragma unroll
        for (int t = 0; t < 21; ++t) acc[t] = wave_sum(acc[t]);
        if (lane == 0) {
#pragma unroll
            for (int t = 0; t < 21; ++t) atomicAdd(&T[t], acc[t]);
        }
    }
}

// ---------------------------------------------------------------------------
// Kernel 4: per-batch epilogue. 64 blocks x 64 threads spreads across CUs.
// ---------------------------------------------------------------------------
__global__ __launch_bounds__(64) void k_out(const float* __restrict__ x,
                                            const float* __restrict__ cc,
                                            const float* __restrict__ bbv,
                                            const float* __restrict__ bais,
                                            const float* __restrict__ T,
                                            const float* __restrict__ H,
                                            const float* __restrict__ v,
                                            const float* __restrict__ w,
                                            float* __restrict__ out) {
    int b = blockIdx.x * 64 + threadIdx.x;
    if (b >= BATCH) return;
    float xv[NFEAT];
#pragma unroll
    for (int j = 0; j < NFEAT; ++j) xv[j] = x[b * NFEAT + j];
    float u[21];
#pragma unroll
    for (int j = 0; j < NFEAT; ++j) {
#pragma unroll
        for (int m = 0; m < 3; ++m) {
            float d = xv[j] - cc[j * 3 + m];
            float bv = bbv[j * 3 + m];
            u[j * 3 + m] = expf(-(d * d) / (bv * bv));
        }
    }
    float ba = bais[0];
    float r = 2187.0f * ba;
#pragma unroll
    for (int t = 0; t < 21; ++t) r += u[t] * T[t];
    float inv = 1.0f / r;
#pragma unroll
    for (int c = 0; c < NCLS; ++c) {
        float s = 0.f;
#pragma unroll
        for (int t = 0; t < 21; ++t) s += u[t] * H[t * NCLS + c];
        float h = (s + ba * v[c]) * inv + w[c];
        out[b * NCLS + c] = (h >= 0.f) ? h : 0.2f * h;
    }
}

extern "C" void kernel_launch(void* const* d_in, const int* in_sizes, int n_in,
                              void* d_out, int out_size, void* d_ws, size_t ws_size,
                              hipStream_t stream) {
    const float* x    = (const float*)d_in[0];
    const float* c    = (const float*)d_in[1];
    const float* bbv  = (const float*)d_in[2];
    const float* wei  = (const float*)d_in[3];
    const float* bais = (const float*)d_in[4];
    const float* W1   = (const float*)d_in[5];
    const float* b1   = (const float*)d_in[6];
    const float* W2   = (const float*)d_in[7];
    const float* b2   = (const float*)d_in[8];
    const float* W3   = (const float*)d_in[9];
    const float* b3   = (const float*)d_in[10];

    // K and T/H/v/w contiguous: zeroed by k_reduce_wei block (0,0).
    float* ws  = (float*)d_ws;
    float* S   = ws;                         // 21*SSTR (fully overwritten)
    float* K   = S + 21 * SSTR;              // 10*512
    float* T   = K + NCLS * MID;             // 32
    float* H   = T + 32;                     // 224 (21*10 used)
    float* v   = H + 224;                    // 16
    float* w   = v + 16;                     // 16   (T..w = 288)
    float* SW1 = w + 16;                     // 21*512
    float* ws1 = SW1 + 21 * MID;             // 512

    k_reduce_wei<<<dim3(35, 21), 512, 0, stream>>>(wei, S, K);
    k_sw1<<<MID + 270, 256, 0, stream>>>(S, W1, W2, W3, SW1, ws1, K);
    k_h<<<dim3(NCLS + 1, 9), 64, 0, stream>>>(S, SW1, ws1, K, b1, b2, b3, W3,
                                              H, v, w, T);
    k_out<<<(BATCH + 63) / 64, 64, 0, stream>>>(x, c, bbv, bais, T, H, v, w,
                                                (float*)d_out);
}